// Round 1
// baseline (766.073 us; speedup 1.0000x reference)
//
#include <hip/hip_runtime.h>
#include <math.h>

#define NB 32
#define NT 4096
#define ND 512
#define NA 64
#define NCHUNK 16          // t-chunks for context partials
#define TCHUNK (NT / NCHUNK)

// ---------------------------------------------------------------- scores ----
// scores[b,t] = w2 . tanh(W1 @ x[b,t] + b1)
// One thread per (b,t). 64 fp32 accumulators; W1/b1/w2 accessed at
// wave-uniform indices -> scalar loads (SGPR operand in v_fma).
__global__ __launch_bounds__(256) void k_scores(
    const float* __restrict__ x, const float* __restrict__ W1,
    const float* __restrict__ b1, const float* __restrict__ w2,
    float* __restrict__ scores)
{
    int gid = blockIdx.x * 256 + threadIdx.x;            // b*NT + t
    const float4* __restrict__ x4 =
        reinterpret_cast<const float4*>(x) + (size_t)gid * (ND / 4);
    const float4* __restrict__ W4 = reinterpret_cast<const float4*>(W1);

    float acc[NA];
#pragma unroll
    for (int a = 0; a < NA; ++a) acc[a] = 0.f;

#pragma unroll 2
    for (int dq = 0; dq < ND / 4; ++dq) {
        float4 xv = x4[dq];
#pragma unroll
        for (int a = 0; a < NA; ++a) {
            float4 wv = W4[a * (ND / 4) + dq];           // uniform -> s_load
            acc[a] = fmaf(xv.x, wv.x, acc[a]);
            acc[a] = fmaf(xv.y, wv.y, acc[a]);
            acc[a] = fmaf(xv.z, wv.z, acc[a]);
            acc[a] = fmaf(xv.w, wv.w, acc[a]);
        }
    }

    float s = 0.f;
#pragma unroll
    for (int a = 0; a < NA; ++a)
        s += w2[a] * tanhf(acc[a] + b1[a]);
    scores[gid] = s;
}

// --------------------------------------------------------------- softmax ----
// One block per batch row b. Masked softmax over T; masked lanes -> exact 0.
__global__ __launch_bounds__(256) void k_softmax(
    const float* __restrict__ scores, const int* __restrict__ mask,
    float* __restrict__ weights)
{
    __shared__ float e_lds[NT];    // 16 KB
    __shared__ float red[4];

    int b = blockIdx.x;
    const float* srow = scores + (size_t)b * NT;
    const int*   mrow = mask   + (size_t)b * NT;

    // pass 1: masked max (and stash masked scores in LDS)
    float m = -INFINITY;
    for (int i = 0; i < NT / 256; ++i) {
        int t = i * 256 + threadIdx.x;
        float s = srow[t];
        bool valid = (mrow[t] != 0);
        e_lds[t] = valid ? s : -INFINITY;
        if (valid) m = fmaxf(m, s);
    }
#pragma unroll
    for (int off = 32; off; off >>= 1) m = fmaxf(m, __shfl_xor(m, off));
    if ((threadIdx.x & 63) == 0) red[threadIdx.x >> 6] = m;
    __syncthreads();
    m = fmaxf(fmaxf(red[0], red[1]), fmaxf(red[2], red[3]));
    __syncthreads();

    // pass 2: exp + sum
    float sum = 0.f;
    for (int i = 0; i < NT / 256; ++i) {
        int t = i * 256 + threadIdx.x;
        float e = expf(e_lds[t] - m);   // exp(-inf - m) == 0 for masked
        e_lds[t] = e;
        sum += e;
    }
#pragma unroll
    for (int off = 32; off; off >>= 1) sum += __shfl_xor(sum, off);
    if ((threadIdx.x & 63) == 0) red[threadIdx.x >> 6] = sum;
    __syncthreads();
    float total = (red[0] + red[1]) + (red[2] + red[3]);
    float inv = 1.f / total;

    // pass 3: normalize + write
    for (int i = 0; i < NT / 256; ++i) {
        int t = i * 256 + threadIdx.x;
        weights[(size_t)b * NT + t] = e_lds[t] * inv;
    }
}

// ------------------------------------------------------- context partials ---
// block = (b, chunk); thread = d (coalesced). partials[b,chunk,d].
__global__ __launch_bounds__(512) void k_ctx_partial(
    const float* __restrict__ x, const float* __restrict__ weights,
    float* __restrict__ partials)
{
    int b = blockIdx.x >> 4;
    int c = blockIdx.x & (NCHUNK - 1);
    int d = threadIdx.x;

    const float* xp = x + ((size_t)b * NT + (size_t)c * TCHUNK) * ND + d;
    const float* wp = weights + (size_t)b * NT + (size_t)c * TCHUNK;

    float acc = 0.f;
#pragma unroll 4
    for (int t = 0; t < TCHUNK; ++t)
        acc = fmaf(wp[t], xp[(size_t)t * ND], acc);      // wp uniform -> s_load

    partials[(size_t)blockIdx.x * ND + d] = acc;
}

// -------------------------------------------------------- context reduce ----
__global__ __launch_bounds__(256) void k_ctx_reduce(
    const float* __restrict__ partials, float* __restrict__ ctx)
{
    int i = blockIdx.x * 256 + threadIdx.x;   // b*ND + d
    int b = i >> 9;
    int d = i & (ND - 1);
    float s = 0.f;
#pragma unroll
    for (int c = 0; c < NCHUNK; ++c)
        s += partials[((size_t)(b * NCHUNK + c)) * ND + d];
    ctx[i] = s;
}

// ------------------------------------------------------------------ launch --
extern "C" void kernel_launch(void* const* d_in, const int* in_sizes, int n_in,
                              void* d_out, int out_size, void* d_ws, size_t ws_size,
                              hipStream_t stream)
{
    const float* x    = (const float*)d_in[0];
    const int*   mask = (const int*)d_in[1];
    const float* W1   = (const float*)d_in[2];
    const float* b1   = (const float*)d_in[3];
    const float* w2   = (const float*)d_in[4];

    float* ctx     = (float*)d_out;                  // B*D
    float* weights = (float*)d_out + NB * ND;        // B*T
    float* scores   = (float*)d_ws;                  // B*T
    float* partials = (float*)d_ws + NB * NT;        // B*NCHUNK*D

    k_scores<<<NB * NT / 256, 256, 0, stream>>>(x, W1, b1, w2, scores);
    k_softmax<<<NB, 256, 0, stream>>>(scores, mask, weights);
    k_ctx_partial<<<NB * NCHUNK, 512, 0, stream>>>(x, weights, partials);
    k_ctx_reduce<<<NB * ND / 256, 256, 0, stream>>>(partials, ctx);
}

// Round 3
// 232.219 us; speedup vs baseline: 3.2989x; 3.2989x over previous
//
#include <hip/hip_runtime.h>
#include <math.h>

#define NB 32
#define NT 4096
#define ND 512
#define NA 64
#define NCHUNK 16          // t-chunks for context partials
#define TCHUNK (NT / NCHUNK)

// ---------------------------------------------------------------- scores ----
// scores[b,t] = w2 . tanh(W1 @ x[b,t] + b1)
// Register-blocked GEMM. Block = 256 threads computes 256 (b,t)-rows x 64 a.
// Thread tile 8 rows x 8 a-cols. W1 staged in DOUBLE-BUFFERED LDS K-chunks
// (KC=64 floats): staging for chunk c+1 goes to the other buffer, so there
// is no LDS write-after-read hazard by construction; one barrier per chunk
// covers read-after-write. Staging is split (global->reg before compute,
// ds_write after) to hide HBM latency under the FMAs.
// LDS column index is XOR-swizzled by (a>>3): the 8 lanes that read
// a = ag*8+j differ by 8 rows, which no row padding can de-conflict
// (8 rows * stride * 16B === 0 mod 128B); dq^ag spreads them over 8 banks.
#define SB 256             // threads per block
#define ROWS_PB 256        // rows per block -> 512 blocks
#define KC 64              // k-chunk in floats
#define KC4 (KC / 4)       // 16 float4 per a-row
#define NKCH (ND / KC)     // 8 chunks
#define STG ((NA * KC4) / SB)   // 4 staging float4 per thread per chunk

__global__ __launch_bounds__(SB) void k_scores(
    const float* __restrict__ x, const float* __restrict__ W1,
    const float* __restrict__ b1, const float* __restrict__ w2,
    float* __restrict__ scores)
{
    __shared__ float4 w_lds[2][NA * KC4];      // 2 x 16 KB

    const int tid  = threadIdx.x;
    const int ag   = tid & 7;                  // a-group: cols ag*8 .. +7
    const int rgrp = tid >> 3;                 // 32 row-groups x 8 rows
    const size_t row0 = (size_t)blockIdx.x * ROWS_PB + (size_t)rgrp * 8;

    const float4* __restrict__ x4 = reinterpret_cast<const float4*>(x);
    const float4* __restrict__ W4 = reinterpret_cast<const float4*>(W1);

    // stage chunk 0 -> buffer 0 (value for (a,kq) stored at col kq^(a>>3))
#pragma unroll
    for (int r = 0; r < STG; ++r) {
        int i  = r * SB + tid;
        int a  = i >> 4;                       // / KC4
        int kq = i & (KC4 - 1);
        w_lds[0][a * KC4 + (kq ^ (a >> 3))] = W4[a * (ND / 4) + kq];
    }

    float acc[8][8];
#pragma unroll
    for (int i = 0; i < 8; ++i)
#pragma unroll
        for (int j = 0; j < 8; ++j) acc[i][j] = 0.f;

    for (int c = 0; c < NKCH; ++c) {
        __syncthreads();                       // staged chunk c visible

        // issue next chunk's global loads early (latency hides under FMAs)
        float4 nxt[STG];
        if (c + 1 < NKCH) {
#pragma unroll
            for (int r = 0; r < STG; ++r) {
                int i  = r * SB + tid;
                int a  = i >> 4;
                int kq = i & (KC4 - 1);
                nxt[r] = W4[a * (ND / 4) + (c + 1) * KC4 + kq];
            }
        }

        const float4* __restrict__ wl = w_lds[c & 1];
        const size_t xb = (size_t)c * KC4;
#pragma unroll 2
        for (int dq = 0; dq < KC4; ++dq) {
            float4 xv[8];
#pragma unroll
            for (int i = 0; i < 8; ++i)
                xv[i] = x4[(row0 + i) * (ND / 4) + xb + dq];
            const int dsw = dq ^ ag;           // un-swizzle: a>>3 == ag here
            float4 wv[8];
#pragma unroll
            for (int j = 0; j < 8; ++j)
                wv[j] = wl[(ag * 8 + j) * KC4 + dsw];
#pragma unroll
            for (int i = 0; i < 8; ++i)
#pragma unroll
                for (int j = 0; j < 8; ++j) {
                    acc[i][j] = fmaf(xv[i].x, wv[j].x, acc[i][j]);
                    acc[i][j] = fmaf(xv[i].y, wv[j].y, acc[i][j]);
                    acc[i][j] = fmaf(xv[i].z, wv[j].z, acc[i][j]);
                    acc[i][j] = fmaf(xv[i].w, wv[j].w, acc[i][j]);
                }
        }

        // write next chunk into the OTHER buffer (no WAR hazard possible)
        if (c + 1 < NKCH) {
            float4* __restrict__ wld = w_lds[(c + 1) & 1];
#pragma unroll
            for (int r = 0; r < STG; ++r) {
                int i  = r * SB + tid;
                int a  = i >> 4;
                int kq = i & (KC4 - 1);
                wld[a * KC4 + (kq ^ (a >> 3))] = nxt[r];
            }
        }
    }

    // epilogue: p_i = sum_j w2[ag*8+j] * tanh(acc[i][j] + b1[ag*8+j])
    float b1v[8], w2v[8];
#pragma unroll
    for (int j = 0; j < 8; ++j) {
        b1v[j] = b1[ag * 8 + j];
        w2v[j] = w2[ag * 8 + j];
    }
    float p[8];
#pragma unroll
    for (int i = 0; i < 8; ++i) {
        float s = 0.f;
#pragma unroll
        for (int j = 0; j < 8; ++j)
            s += w2v[j] * tanhf(acc[i][j] + b1v[j]);
        p[i] = s;
    }
#pragma unroll
    for (int off = 1; off < 8; off <<= 1)
#pragma unroll
        for (int i = 0; i < 8; ++i) p[i] += __shfl_xor(p[i], off);

    if (ag == 0) {
#pragma unroll
        for (int i = 0; i < 8; ++i) scores[row0 + i] = p[i];
    }
}

// --------------------------------------------------------------- softmax ----
__global__ __launch_bounds__(256) void k_softmax(
    const float* __restrict__ scores, const int* __restrict__ mask,
    float* __restrict__ weights)
{
    __shared__ float e_lds[NT];    // 16 KB
    __shared__ float red[4];

    int b = blockIdx.x;
    const float* srow = scores + (size_t)b * NT;
    const int*   mrow = mask   + (size_t)b * NT;

    float m = -INFINITY;
    for (int i = 0; i < NT / 256; ++i) {
        int t = i * 256 + threadIdx.x;
        float s = srow[t];
        bool valid = (mrow[t] != 0);
        e_lds[t] = valid ? s : -INFINITY;
        if (valid) m = fmaxf(m, s);
    }
#pragma unroll
    for (int off = 32; off; off >>= 1) m = fmaxf(m, __shfl_xor(m, off));
    if ((threadIdx.x & 63) == 0) red[threadIdx.x >> 6] = m;
    __syncthreads();
    m = fmaxf(fmaxf(red[0], red[1]), fmaxf(red[2], red[3]));
    __syncthreads();

    float sum = 0.f;
    for (int i = 0; i < NT / 256; ++i) {
        int t = i * 256 + threadIdx.x;
        float e = expf(e_lds[t] - m);
        e_lds[t] = e;
        sum += e;
    }
#pragma unroll
    for (int off = 32; off; off >>= 1) sum += __shfl_xor(sum, off);
    if ((threadIdx.x & 63) == 0) red[threadIdx.x >> 6] = sum;
    __syncthreads();
    float total = (red[0] + red[1]) + (red[2] + red[3]);
    float inv = 1.f / total;

    for (int i = 0; i < NT / 256; ++i) {
        int t = i * 256 + threadIdx.x;
        weights[(size_t)b * NT + t] = e_lds[t] * inv;
    }
}

// ------------------------------------------------------- context partials ---
__global__ __launch_bounds__(512) void k_ctx_partial(
    const float* __restrict__ x, const float* __restrict__ weights,
    float* __restrict__ partials)
{
    int b = blockIdx.x >> 4;
    int c = blockIdx.x & (NCHUNK - 1);
    int d = threadIdx.x;

    const float* xp = x + ((size_t)b * NT + (size_t)c * TCHUNK) * ND + d;
    const float* wp = weights + (size_t)b * NT + (size_t)c * TCHUNK;

    float acc = 0.f;
#pragma unroll 4
    for (int t = 0; t < TCHUNK; ++t)
        acc = fmaf(wp[t], xp[(size_t)t * ND], acc);

    partials[(size_t)blockIdx.x * ND + d] = acc;
}

// -------------------------------------------------------- context reduce ----
__global__ __launch_bounds__(256) void k_ctx_reduce(
    const float* __restrict__ partials, float* __restrict__ ctx)
{
    int i = blockIdx.x * 256 + threadIdx.x;   // b*ND + d
    int b = i >> 9;
    int d = i & (ND - 1);
    float s = 0.f;
#pragma unroll
    for (int c = 0; c < NCHUNK; ++c)
        s += partials[((size_t)(b * NCHUNK + c)) * ND + d];
    ctx[i] = s;
}

// ------------------------------------------------------------------ launch --
extern "C" void kernel_launch(void* const* d_in, const int* in_sizes, int n_in,
                              void* d_out, int out_size, void* d_ws, size_t ws_size,
                              hipStream_t stream)
{
    const float* x    = (const float*)d_in[0];
    const int*   mask = (const int*)d_in[1];
    const float* W1   = (const float*)d_in[2];
    const float* b1   = (const float*)d_in[3];
    const float* w2   = (const float*)d_in[4];

    float* ctx     = (float*)d_out;                  // B*D
    float* weights = (float*)d_out + NB * ND;        // B*T
    float* scores   = (float*)d_ws;                  // B*T
    float* partials = (float*)d_ws + NB * NT;        // B*NCHUNK*D

    k_scores<<<(NB * NT) / ROWS_PB, SB, 0, stream>>>(x, W1, b1, w2, scores);
    k_softmax<<<NB, 256, 0, stream>>>(scores, mask, weights);
    k_ctx_partial<<<NB * NCHUNK, 512, 0, stream>>>(x, weights, partials);
    k_ctx_reduce<<<NB * ND / 256, 256, 0, stream>>>(partials, ctx);
}